// Round 1
// baseline (2224.830 us; speedup 1.0000x reference)
//
#include <hip/hip_runtime.h>

#define T_    8
#define H_    28
#define W_    28
#define NSP   6272      // T*H*W
#define NTOKS 6273
#define DIM   192
#define HEADS 2
#define HD    96
#define SCALE_ 0.10206207261596575f   // 96^-0.5
#define EPS_  1e-5f
#define QB    8
#define KB    512
#define QBLKS ((NTOKS + QB - 1) / QB)   // 785

// ---------------- Kernel 1: qkv = x @ qkv_w^T + qkv_b ----------------
__global__ __launch_bounds__(256) void qkv_gemm(
    const float* __restrict__ x, const float* __restrict__ w,
    const float* __restrict__ b, float* __restrict__ qkv)
{
    __shared__ float xs[8][DIM];
    int row0 = blockIdx.x * 8;
    int t = threadIdx.x;
    for (int i = t; i < 8 * DIM; i += 256) {
        int r = i / DIM, c = i % DIM;
        xs[r][c] = (row0 + r < NTOKS) ? x[(size_t)(row0 + r) * DIM + c] : 0.f;
    }
    __syncthreads();
    for (int rep = 0; rep < 3; ++rep) {
        int j = t + rep * 256;
        if (j >= 3 * DIM) break;
        const float4* wr = (const float4*)(w + (size_t)j * DIM);
        float acc[8];
        #pragma unroll
        for (int r = 0; r < 8; ++r) acc[r] = 0.f;
        for (int k4 = 0; k4 < DIM / 4; ++k4) {
            float4 wv = wr[k4];
            #pragma unroll
            for (int r = 0; r < 8; ++r) {
                acc[r] += xs[r][k4*4+0]*wv.x + xs[r][k4*4+1]*wv.y
                        + xs[r][k4*4+2]*wv.z + xs[r][k4*4+3]*wv.w;
            }
        }
        float bj = b[j];
        #pragma unroll
        for (int r = 0; r < 8; ++r) {
            int row = row0 + r;
            if (row < NTOKS) qkv[(size_t)row * 576 + j] = acc[r] + bj;
        }
    }
}

// ------------- Kernel 2: depthwise conv3d pool + LayerNorm -------------
// grid.x = HEADS*NTOKS (h, tok), grid.y = 3 (q,k,v), block = 128
__global__ __launch_bounds__(128) void pool_ln(
    const float* __restrict__ qkv,
    const float* __restrict__ wq, const float* __restrict__ wk, const float* __restrict__ wv,
    const float* __restrict__ gq, const float* __restrict__ bq,
    const float* __restrict__ gk, const float* __restrict__ bk,
    const float* __restrict__ gv, const float* __restrict__ bv,
    float* __restrict__ qp, float* __restrict__ kp, float* __restrict__ vp)
{
    int which = blockIdx.y;
    const float* pw = which == 0 ? wq : (which == 1 ? wk : wv);
    const float* g  = which == 0 ? gq : (which == 1 ? gk : gv);
    const float* bb = which == 0 ? bq : (which == 1 ? bk : bv);
    float* outp     = which == 0 ? qp : (which == 1 ? kp : vp);

    int h   = blockIdx.x / NTOKS;
    int tok = blockIdx.x % NTOKS;
    int c   = threadIdx.x;

    float val = 0.f;
    if (c < HD) {
        int base_col = which * DIM + h * HD + c;
        if (tok == 0) {
            val = qkv[base_col];
        } else {
            int sp  = tok - 1;
            int tq  = sp / (H_ * W_);
            int rem = sp % (H_ * W_);
            int hq  = rem / W_;
            int wq_ = rem % W_;
            const float* wc = pw + c * 27;
            #pragma unroll
            for (int dt = -1; dt <= 1; ++dt) {
                int tt = tq + dt; if (tt < 0 || tt >= T_) continue;
                #pragma unroll
                for (int dy = -1; dy <= 1; ++dy) {
                    int yy = hq + dy; if (yy < 0 || yy >= H_) continue;
                    #pragma unroll
                    for (int dx = -1; dx <= 1; ++dx) {
                        int xx = wq_ + dx; if (xx < 0 || xx >= W_) continue;
                        int tok2 = 1 + (tt * H_ + yy) * W_ + xx;
                        val += wc[(dt+1)*9 + (dy+1)*3 + (dx+1)]
                             * qkv[(size_t)tok2 * 576 + base_col];
                    }
                }
            }
        }
    }
    __shared__ float r1[128], r2[128];
    r1[threadIdx.x] = (c < HD) ? val : 0.f;
    r2[threadIdx.x] = (c < HD) ? val * val : 0.f;
    __syncthreads();
    for (int s = 64; s > 0; s >>= 1) {
        if (threadIdx.x < s) { r1[threadIdx.x] += r1[threadIdx.x+s]; r2[threadIdx.x] += r2[threadIdx.x+s]; }
        __syncthreads();
    }
    float m   = r1[0] * (1.f / HD);
    float var = r2[0] * (1.f / HD) - m * m;
    float inv = rsqrtf(var + EPS_);
    if (c < HD)
        outp[((size_t)h * NTOKS + tok) * HD + c] = (val - m) * inv * g[c] + bb[c];
}

// ------------- Kernel 3: rel-pos bias component dot products -------------
// grid = HEADS*NSP, block = 64: threads 0..7 -> bt, 8..35 -> bh, 36..63 -> bw
__global__ __launch_bounds__(64) void relbias(
    const float* __restrict__ qp,
    const float* __restrict__ rel_h, const float* __restrict__ rel_w,
    const float* __restrict__ rel_t,
    float* __restrict__ bt, float* __restrict__ bh, float* __restrict__ bw)
{
    int h  = blockIdx.x / NSP;
    int sp = blockIdx.x % NSP;
    __shared__ float qv[HD];
    int t = threadIdx.x;
    for (int i = t; i < HD; i += 64)
        qv[i] = qp[((size_t)h * NTOKS + sp + 1) * HD + i];
    __syncthreads();
    int tq  = sp / (H_ * W_);
    int rem = sp % (H_ * W_);
    int hq  = rem / W_;
    int wq  = rem % W_;
    const float* row;
    float* outp;
    if (t < 8)       { row = rel_t + (size_t)(tq - t        + (T_ - 1)) * HD; outp = bt + ((size_t)h*NSP + sp)*8  + t;      }
    else if (t < 36) { row = rel_h + (size_t)(hq - (t - 8)  + (H_ - 1)) * HD; outp = bh + ((size_t)h*NSP + sp)*28 + (t-8);  }
    else             { row = rel_w + (size_t)(wq - (t - 36) + (W_ - 1)) * HD; outp = bw + ((size_t)h*NSP + sp)*28 + (t-36); }
    float acc = 0.f;
    for (int c = 0; c < HD; ++c) acc += qv[c] * row[c];
    *outp = acc;
}

// ------------- Kernel 4: flash attention with decomposed bias -------------
// grid = HEADS*QBLKS, block = 256
__global__ __launch_bounds__(256) void attn_kernel(
    const float* __restrict__ qp, const float* __restrict__ kp,
    const float* __restrict__ vp,
    const float* __restrict__ btp, const float* __restrict__ bhp,
    const float* __restrict__ bwp,
    float* __restrict__ pre)
{
    __shared__ __align__(16) float ptile[KB][QB];   // 16 KB, [key][query]
    __shared__ __align__(16) float qv[QB][HD];
    __shared__ float bias[QB][64];                  // [0..7]=bt [8..35]=bh [36..63]=bw
    __shared__ float mrun[QB], lrun[QB], alph[QB], tmax[QB];
    __shared__ __align__(16) float comb[QB][HD];

    int h  = blockIdx.x / QBLKS;
    int qb = blockIdx.x % QBLKS;
    int q0 = qb * QB;
    int tid = threadIdx.x;

    for (int i = tid; i < QB * HD; i += 256) {
        int q = i / HD, c = i % HD;
        int tok = q0 + q; if (tok > NTOKS - 1) tok = NTOKS - 1;
        qv[q][c] = qp[((size_t)h * NTOKS + tok) * HD + c];
    }
    for (int i = tid; i < QB * 64; i += 256) {
        int q = i >> 6, k = i & 63;
        int tok = q0 + q;
        float v = 0.f;
        if (tok >= 1 && tok < NTOKS) {   // spatial query only
            int sp = tok - 1;
            if (k < 8)       v = btp[((size_t)h * NSP + sp) * 8  + k];
            else if (k < 36) v = bhp[((size_t)h * NSP + sp) * 28 + (k - 8)];
            else             v = bwp[((size_t)h * NSP + sp) * 28 + (k - 36)];
        }
        bias[q][k] = v;
    }
    if (tid < QB) { mrun[tid] = -3e38f; lrun[tid] = 0.f; }

    float acc[QB];
    #pragma unroll
    for (int q = 0; q < QB; ++q) acc[q] = 0.f;
    int oc    = tid % HD;      // output channel
    int ohalf = tid / HD;      // 0,1 active in PV phase; 2 idle
    int g     = tid >> 5;      // query group for reductions
    int lane  = tid & 31;

    __syncthreads();

    const int ntiles = (NTOKS + KB - 1) / KB;
    for (int tile = 0; tile < ntiles; ++tile) {
        int base = tile * KB;
        // ---- score phase: 2 keys per thread, 8 queries register-blocked ----
        {
            int j[2]; j[0] = base + tid; j[1] = base + 256 + tid;
            float d[2][QB];
            #pragma unroll
            for (int q = 0; q < QB; ++q) { d[0][q] = 0.f; d[1][q] = 0.f; }
            int j0c = j[0] > NTOKS - 1 ? NTOKS - 1 : j[0];
            int j1c = j[1] > NTOKS - 1 ? NTOKS - 1 : j[1];
            const float4* kr0 = (const float4*)(kp + ((size_t)h * NTOKS + j0c) * HD);
            const float4* kr1 = (const float4*)(kp + ((size_t)h * NTOKS + j1c) * HD);
            for (int c4 = 0; c4 < HD / 4; ++c4) {
                float4 ka = kr0[c4];
                float4 kb = kr1[c4];
                #pragma unroll
                for (int q = 0; q < QB; ++q) {
                    float4 qq = ((const float4*)qv[q])[c4];
                    d[0][q] += ka.x*qq.x + ka.y*qq.y + ka.z*qq.z + ka.w*qq.w;
                    d[1][q] += kb.x*qq.x + kb.y*qq.y + kb.z*qq.z + kb.w*qq.w;
                }
            }
            #pragma unroll
            for (int u = 0; u < 2; ++u) {
                int jl = u * 256 + tid;
                if (j[u] < NTOKS) {
                    int kt = 0, kh = 0, kw = 0;
                    int spk = (j[u] >= 1);
                    if (spk) {
                        int jj = j[u] - 1;
                        kt = jj / (H_ * W_);
                        int rem = jj - kt * (H_ * W_);
                        kh = rem / W_;
                        kw = rem - kh * W_;
                    }
                    float s[QB];
                    #pragma unroll
                    for (int q = 0; q < QB; ++q) {
                        s[q] = d[u][q] * SCALE_;
                        if (spk) s[q] += bias[q][kt] + bias[q][8 + kh] + bias[q][36 + kw];
                    }
                    *((float4*)ptile[jl])     = make_float4(s[0], s[1], s[2], s[3]);
                    *((float4*)ptile[jl] + 1) = make_float4(s[4], s[5], s[6], s[7]);
                } else {
                    *((float4*)ptile[jl])     = make_float4(-3e38f, -3e38f, -3e38f, -3e38f);
                    *((float4*)ptile[jl] + 1) = make_float4(-3e38f, -3e38f, -3e38f, -3e38f);
                }
            }
        }
        __syncthreads();
        // ---- per-query tile max (32 threads per query) ----
        {
            float mx = -3e38f;
            for (int k = lane; k < KB; k += 32) mx = fmaxf(mx, ptile[k][g]);
            #pragma unroll
            for (int off = 16; off > 0; off >>= 1) mx = fmaxf(mx, __shfl_xor(mx, off, 64));
            if (lane == 0) tmax[g] = mx;
        }
        __syncthreads();
        if (tid < QB) {
            float mo = mrun[tid];
            float mn = fmaxf(mo, tmax[tid]);
            alph[tid] = __expf(mo - mn);
            mrun[tid] = mn;
        }
        __syncthreads();
        // ---- exp + per-query sum ----
        {
            float mn = mrun[g];
            float sm = 0.f;
            for (int k = lane; k < KB; k += 32) {
                float p = __expf(ptile[k][g] - mn);
                ptile[k][g] = p;
                sm += p;
            }
            #pragma unroll
            for (int off = 16; off > 0; off >>= 1) sm += __shfl_xor(sm, off, 64);
            if (lane == 0) lrun[g] = alph[g] * lrun[g] + sm;
        }
        __syncthreads();
        // ---- PV accumulate (threads 0..191: channel x key-half) ----
        if (ohalf < 2) {
            #pragma unroll
            for (int q = 0; q < QB; ++q) acc[q] *= alph[q];
            int kmax = NTOKS - base; if (kmax > KB) kmax = KB;
            int kend = (ohalf + 1) * (KB / 2); if (kend > kmax) kend = kmax;
            for (int k = ohalf * (KB / 2); k < kend; ++k) {
                float vv = vp[((size_t)h * NTOKS + base + k) * HD + oc];
                float4 p0 = *((const float4*)ptile[k]);
                float4 p1 = *((const float4*)ptile[k] + 1);
                acc[0] += p0.x * vv; acc[1] += p0.y * vv;
                acc[2] += p0.z * vv; acc[3] += p0.w * vv;
                acc[4] += p1.x * vv; acc[5] += p1.y * vv;
                acc[6] += p1.z * vv; acc[7] += p1.w * vv;
            }
        }
        __syncthreads();
    }
    // ---- combine halves, normalize, residual, store ----
    if (ohalf == 1) {
        #pragma unroll
        for (int q = 0; q < QB; ++q) comb[q][oc] = acc[q];
    }
    __syncthreads();
    if (ohalf == 0) {
        #pragma unroll
        for (int q = 0; q < QB; ++q) {
            int tok = q0 + q;
            if (tok < NTOKS) {
                float o = (acc[q] + comb[q][oc]) / lrun[q];
                if (tok >= 1) o += qv[q][oc];           // residual: pooled q
                pre[(size_t)tok * DIM + h * HD + oc] = o;
            }
        }
    }
}

// ---------------- Kernel 5: out = pre @ proj_w^T + proj_b ----------------
__global__ __launch_bounds__(192) void proj_gemm(
    const float* __restrict__ pre, const float* __restrict__ w,
    const float* __restrict__ b, float* __restrict__ out)
{
    __shared__ float xs[8][DIM];
    int row0 = blockIdx.x * 8;
    int t = threadIdx.x;
    for (int i = t; i < 8 * DIM; i += 192) {
        int r = i / DIM, c = i % DIM;
        xs[r][c] = (row0 + r < NTOKS) ? pre[(size_t)(row0 + r) * DIM + c] : 0.f;
    }
    __syncthreads();
    int j = t;  // 0..191
    const float4* wr = (const float4*)(w + (size_t)j * DIM);
    float acc[8];
    #pragma unroll
    for (int r = 0; r < 8; ++r) acc[r] = 0.f;
    for (int k4 = 0; k4 < DIM / 4; ++k4) {
        float4 wv = wr[k4];
        #pragma unroll
        for (int r = 0; r < 8; ++r) {
            acc[r] += xs[r][k4*4+0]*wv.x + xs[r][k4*4+1]*wv.y
                    + xs[r][k4*4+2]*wv.z + xs[r][k4*4+3]*wv.w;
        }
    }
    float bj = b[j];
    #pragma unroll
    for (int r = 0; r < 8; ++r) {
        int row = row0 + r;
        if (row < NTOKS) out[(size_t)row * DIM + j] = acc[r] + bj;
    }
}

extern "C" void kernel_launch(void* const* d_in, const int* in_sizes, int n_in,
                              void* d_out, int out_size, void* d_ws, size_t ws_size,
                              hipStream_t stream) {
    (void)in_sizes; (void)n_in; (void)out_size; (void)ws_size;
    const float* x      = (const float*)d_in[0];
    const float* qkv_w  = (const float*)d_in[1];
    const float* qkv_b  = (const float*)d_in[2];
    const float* proj_w = (const float*)d_in[3];
    const float* proj_b = (const float*)d_in[4];
    const float* pool_q = (const float*)d_in[5];
    const float* pool_k = (const float*)d_in[6];
    const float* pool_v = (const float*)d_in[7];
    const float* gq     = (const float*)d_in[8];
    const float* bq     = (const float*)d_in[9];
    const float* gk     = (const float*)d_in[10];
    const float* bk     = (const float*)d_in[11];
    const float* gv     = (const float*)d_in[12];
    const float* bv     = (const float*)d_in[13];
    const float* rel_h  = (const float*)d_in[14];
    const float* rel_w  = (const float*)d_in[15];
    const float* rel_t  = (const float*)d_in[16];

    float* ws  = (float*)d_ws;
    float* qkv = ws;  ws += (size_t)NTOKS * 576;
    float* qp  = ws;  ws += (size_t)HEADS * NTOKS * HD;
    float* kp  = ws;  ws += (size_t)HEADS * NTOKS * HD;
    float* vp  = ws;  ws += (size_t)HEADS * NTOKS * HD;
    float* bt  = ws;  ws += (size_t)HEADS * NSP * 8;
    float* bh  = ws;  ws += (size_t)HEADS * NSP * 28;
    float* bw  = ws;  ws += (size_t)HEADS * NSP * 28;
    float* pre = ws;  ws += (size_t)NTOKS * DIM;

    qkv_gemm<<<(NTOKS + 7) / 8, 256, 0, stream>>>(x, qkv_w, qkv_b, qkv);
    pool_ln<<<dim3(HEADS * NTOKS, 3), 128, 0, stream>>>(
        qkv, pool_q, pool_k, pool_v, gq, bq, gk, bk, gv, bv, qp, kp, vp);
    relbias<<<HEADS * NSP, 64, 0, stream>>>(qp, rel_h, rel_w, rel_t, bt, bh, bw);
    attn_kernel<<<HEADS * QBLKS, 256, 0, stream>>>(qp, kp, vp, bt, bh, bw, pre);
    proj_gemm<<<(NTOKS + 7) / 8, 192, 0, stream>>>(pre, proj_w, proj_b, (float*)d_out);
}

// Round 2
// 559.439 us; speedup vs baseline: 3.9769x; 3.9769x over previous
//
#include <hip/hip_runtime.h>

#define T_    8
#define H_    28
#define W_    28
#define NSP   6272      // T*H*W
#define NTOKS 6273
#define DIM   192
#define HEADS 2
#define HD    96
#define SCALE_ 0.10206207261596575f   // 96^-0.5
#define EPS_  1e-5f

#define QT    16
#define KT    64
#define QB2   ((NTOKS + QT - 1) / QT)   // 393
#define VT_LD 6400                      // padded vbT row length (tokens)

using bf16x8 = __attribute__((ext_vector_type(8))) short;
using f32x4  = __attribute__((ext_vector_type(4))) float;
typedef unsigned short u16;
typedef unsigned int   u32;

__device__ inline u16 f2b(float f) {   // fp32 -> bf16 bits, RNE
    u32 u = __builtin_bit_cast(u32, f);
    u += 0x7fffu + ((u >> 16) & 1u);
    return (u16)(u >> 16);
}

// ---------------- Kernel 1: qkv = x @ qkv_w^T + qkv_b ----------------
__global__ __launch_bounds__(256) void qkv_gemm(
    const float* __restrict__ x, const float* __restrict__ w,
    const float* __restrict__ b, float* __restrict__ qkv)
{
    __shared__ float xs[8][DIM];
    int row0 = blockIdx.x * 8;
    int t = threadIdx.x;
    for (int i = t; i < 8 * DIM; i += 256) {
        int r = i / DIM, c = i % DIM;
        xs[r][c] = (row0 + r < NTOKS) ? x[(size_t)(row0 + r) * DIM + c] : 0.f;
    }
    __syncthreads();
    for (int rep = 0; rep < 3; ++rep) {
        int j = t + rep * 256;
        if (j >= 3 * DIM) break;
        const float4* wr = (const float4*)(w + (size_t)j * DIM);
        float acc[8];
        #pragma unroll
        for (int r = 0; r < 8; ++r) acc[r] = 0.f;
        for (int k4 = 0; k4 < DIM / 4; ++k4) {
            float4 wv = wr[k4];
            #pragma unroll
            for (int r = 0; r < 8; ++r) {
                acc[r] += xs[r][k4*4+0]*wv.x + xs[r][k4*4+1]*wv.y
                        + xs[r][k4*4+2]*wv.z + xs[r][k4*4+3]*wv.w;
            }
        }
        float bj = b[j];
        #pragma unroll
        for (int r = 0; r < 8; ++r) {
            int row = row0 + r;
            if (row < NTOKS) qkv[(size_t)row * 576 + j] = acc[r] + bj;
        }
    }
}

// ------------- Kernel 2: depthwise conv3d pool + LayerNorm -------------
// grid.x = HEADS*NTOKS, grid.y = 3 (q,k,v), block = 128
// q -> fp32 qp + bf16 qbb ; k -> bf16 kbb ; v -> bf16 vbb
__global__ __launch_bounds__(128) void pool_ln(
    const float* __restrict__ qkv,
    const float* __restrict__ wq, const float* __restrict__ wk, const float* __restrict__ wv,
    const float* __restrict__ gq, const float* __restrict__ bq,
    const float* __restrict__ gk, const float* __restrict__ bk,
    const float* __restrict__ gv, const float* __restrict__ bv,
    float* __restrict__ qp, u16* __restrict__ qbb,
    u16* __restrict__ kbb, u16* __restrict__ vbb)
{
    int which = blockIdx.y;
    const float* pw = which == 0 ? wq : (which == 1 ? wk : wv);
    const float* g  = which == 0 ? gq : (which == 1 ? gk : gv);
    const float* bb = which == 0 ? bq : (which == 1 ? bk : bv);

    int h   = blockIdx.x / NTOKS;
    int tok = blockIdx.x % NTOKS;
    int c   = threadIdx.x;

    float val = 0.f;
    if (c < HD) {
        int base_col = which * DIM + h * HD + c;
        if (tok == 0) {
            val = qkv[base_col];
        } else {
            int sp  = tok - 1;
            int tq  = sp / (H_ * W_);
            int rem = sp % (H_ * W_);
            int hq  = rem / W_;
            int wq_ = rem % W_;
            const float* wc = pw + c * 27;
            #pragma unroll
            for (int dt = -1; dt <= 1; ++dt) {
                int tt = tq + dt; if (tt < 0 || tt >= T_) continue;
                #pragma unroll
                for (int dy = -1; dy <= 1; ++dy) {
                    int yy = hq + dy; if (yy < 0 || yy >= H_) continue;
                    #pragma unroll
                    for (int dx = -1; dx <= 1; ++dx) {
                        int xx = wq_ + dx; if (xx < 0 || xx >= W_) continue;
                        int tok2 = 1 + (tt * H_ + yy) * W_ + xx;
                        val += wc[(dt+1)*9 + (dy+1)*3 + (dx+1)]
                             * qkv[(size_t)tok2 * 576 + base_col];
                    }
                }
            }
        }
    }
    __shared__ float r1[128], r2[128];
    r1[threadIdx.x] = (c < HD) ? val : 0.f;
    r2[threadIdx.x] = (c < HD) ? val * val : 0.f;
    __syncthreads();
    for (int s = 64; s > 0; s >>= 1) {
        if (threadIdx.x < s) { r1[threadIdx.x] += r1[threadIdx.x+s]; r2[threadIdx.x] += r2[threadIdx.x+s]; }
        __syncthreads();
    }
    float m   = r1[0] * (1.f / HD);
    float var = r2[0] * (1.f / HD) - m * m;
    float inv = rsqrtf(var + EPS_);
    if (c < HD) {
        float o = (val - m) * inv * g[c] + bb[c];
        size_t off = ((size_t)h * NTOKS + tok) * HD + c;
        if (which == 0)      { qp[off] = o; qbb[off] = f2b(o); }
        else if (which == 1) { kbb[off] = f2b(o); }
        else                 { vbb[off] = f2b(o); }
    }
}

// ------------- Kernel 2b: transpose V to [h][c][tok] (padded rows) -------------
// grid = (ceil(NTOKS/128), HEADS), block = 256
__global__ __launch_bounds__(256) void vtrans(
    const u16* __restrict__ vbb, u16* __restrict__ vbT)
{
    __shared__ u16 tls[128][104];
    int h  = blockIdx.y;
    int t0 = blockIdx.x * 128;
    int tid = threadIdx.x;
    #pragma unroll
    for (int it = 0; it < 24; ++it) {           // 128*48 dwords
        int idx = tid + it * 256;
        int row = idx / 48, col = idx % 48;
        int tok = t0 + row; if (tok > NTOKS - 1) tok = NTOKS - 1;
        *(u32*)&tls[row][col*2] = *(const u32*)(vbb + ((size_t)h * NTOKS + tok) * HD + col*2);
    }
    __syncthreads();
    #pragma unroll
    for (int it = 0; it < 24; ++it) {           // 96*64 dwords
        int idx = tid + it * 256;
        int c = idx / 64, tp = idx % 64;
        u32 lo = tls[tp*2][c], hi = tls[tp*2+1][c];
        *(u32*)(vbT + ((size_t)h * HD + c) * VT_LD + t0 + tp*2) = lo | (hi << 16);
    }
}

// ------------- Kernel 3: rel-pos bias component dot products -------------
__global__ __launch_bounds__(64) void relbias(
    const float* __restrict__ qp,
    const float* __restrict__ rel_h, const float* __restrict__ rel_w,
    const float* __restrict__ rel_t,
    float* __restrict__ bt, float* __restrict__ bh, float* __restrict__ bw)
{
    int h  = blockIdx.x / NSP;
    int sp = blockIdx.x % NSP;
    __shared__ float qv[HD];
    int t = threadIdx.x;
    for (int i = t; i < HD; i += 64)
        qv[i] = qp[((size_t)h * NTOKS + sp + 1) * HD + i];
    __syncthreads();
    int tq  = sp / (H_ * W_);
    int rem = sp % (H_ * W_);
    int hq  = rem / W_;
    int wq  = rem % W_;
    const float* row;
    float* outp;
    if (t < 8)       { row = rel_t + (size_t)(tq - t        + (T_ - 1)) * HD; outp = bt + ((size_t)h*NSP + sp)*8  + t;      }
    else if (t < 36) { row = rel_h + (size_t)(hq - (t - 8)  + (H_ - 1)) * HD; outp = bh + ((size_t)h*NSP + sp)*28 + (t-8);  }
    else             { row = rel_w + (size_t)(wq - (t - 36) + (W_ - 1)) * HD; outp = bw + ((size_t)h*NSP + sp)*28 + (t-36); }
    float acc = 0.f;
    for (int c = 0; c < HD; ++c) acc += qv[c] * row[c];
    *outp = acc;
}

// ------------- Kernel 4: MFMA flash attention with decomposed bias -------------
// grid = HEADS*QB2, block = 256 (4 waves)
// Layouts (m89/m120-verified): A[m=lane&15][k=quad*8+j], B[k=quad*8+j][n=lane&15],
// C/D: col=lane&15, row=quad*4+reg.
__global__ __launch_bounds__(256, 4) void attn_mfma(
    const u16* __restrict__ qb, const u16* __restrict__ kb,
    const u16* __restrict__ vbT, const float* __restrict__ qp,
    const float* __restrict__ btp, const float* __restrict__ bhp,
    const float* __restrict__ bwp, float* __restrict__ pre)
{
    __shared__ __align__(16) u16  kls[64 * 104];   // K tile [key][c], pad 104
    __shared__ __align__(16) u16  vls[96 * 72];    // V^T tile [c][key], pad 72
    __shared__ __align__(16) float sls[16 * 68];   // raw scores [q][key], pad 68
    __shared__ __align__(16) u16  pls[16 * 72];    // probs bf16 [q][key], pad 72
    __shared__ float biasL[QT * 64];
    __shared__ float alphL[QT];
    __shared__ float lrunL[QT];

    const int h   = blockIdx.x / QB2;
    const int q0  = (blockIdx.x % QB2) * QT;
    const int tid = threadIdx.x;
    const int w    = tid >> 6;
    const int lane = tid & 63;
    const int quad = lane >> 4;
    const int l16  = lane & 15;

    // bias table for this block's 16 query rows
    for (int i = tid; i < QT * 64; i += 256) {
        int q = i >> 6, kk = i & 63;
        int tok = q0 + q;
        float v = 0.f;
        if (tok >= 1 && tok < NTOKS) {
            int sp = tok - 1;
            if (kk < 8)       v = btp[((size_t)h * NSP + sp) * 8  + kk];
            else if (kk < 36) v = bhp[((size_t)h * NSP + sp) * 28 + (kk - 8)];
            else              v = bwp[((size_t)h * NSP + sp) * 28 + (kk - 36)];
        }
        biasL[i] = v;
    }

    // Q fragments: 3 chunks of K=32 channels
    bf16x8 aq[3];
    {
        int tok = q0 + l16; if (tok > NTOKS - 1) tok = NTOKS - 1;
        const u16* qrow = qb + ((size_t)h * NTOKS + tok) * HD;
        #pragma unroll
        for (int c = 0; c < 3; ++c)
            aq[c] = *(const bf16x8*)(qrow + c * 32 + quad * 8);
    }

    const int r  = tid >> 4;   // softmax row served by this thread (0..15)
    const int c0 = tid & 15;
    float mrun = -3e30f, lrun = 0.f;

    // PV accumulators: wave w owns channel n-tiles {w} and {w+4} (w<2)
    f32x4 acc0 = {0,0,0,0}, acc1 = {0,0,0,0};
    const int nt0 = w, nt1 = w + 4;
    const bool has2 = (w < 2);

    const int NTILES = (NTOKS + KT - 1) / KT;   // 99
    for (int tile = 0; tile < NTILES; ++tile) {
        const int kb0 = tile * KT;
        // ---- stage K tile: 64 keys x 96 ch (row copy) ----
        #pragma unroll
        for (int it = 0; it < 3; ++it) {
            int idx4 = tid + it * 256;          // 768 x uint4
            int row = idx4 / 12, col4 = idx4 % 12;
            int key = kb0 + row; if (key > NTOKS - 1) key = NTOKS - 1;
            uint4 v = *(const uint4*)(kb + ((size_t)h * NTOKS + key) * HD + col4 * 8);
            *(uint4*)(kls + row * 104 + col4 * 8) = v;
        }
        // ---- stage V^T tile: 96 ch x 64 keys (row copy from vbT) ----
        #pragma unroll
        for (int it = 0; it < 3; ++it) {
            int idx4 = tid + it * 256;          // 768 x uint4
            int c = idx4 >> 3, col4 = idx4 & 7;
            uint4 v = *(const uint4*)(vbT + ((size_t)h * HD + c) * VT_LD + kb0 + col4 * 8);
            *(uint4*)(vls + c * 72 + col4 * 8) = v;
        }
        __syncthreads();
        // ---- S = Q K^T : this wave's 16 keys ----
        {
            f32x4 accs = {0,0,0,0};
            const u16* krow = kls + (w * 16 + l16) * 104;
            #pragma unroll
            for (int c = 0; c < 3; ++c) {
                bf16x8 bk = *(const bf16x8*)(krow + c * 32 + quad * 8);
                accs = __builtin_amdgcn_mfma_f32_16x16x32_bf16(aq[c], bk, accs, 0, 0, 0);
            }
            #pragma unroll
            for (int rr = 0; rr < 4; ++rr)
                sls[(quad * 4 + rr) * 68 + w * 16 + l16] = accs[rr];
        }
        __syncthreads();
        // ---- softmax: scale + bias, running max, exp, bf16 P ----
        float sv[4];
        float mx = -3e30f;
        #pragma unroll
        for (int i = 0; i < 4; ++i) {
            int col = c0 + i * 16;
            int key = kb0 + col;
            float s = -3e30f;
            if (key < NTOKS) {
                s = sls[r * 68 + col] * SCALE_;
                if (key >= 1) {
                    int sp  = key - 1;
                    int kt  = sp / (H_ * W_);
                    int rem = sp - kt * (H_ * W_);
                    int kh  = rem / W_;
                    int kw  = rem - kh * W_;
                    s += biasL[r * 64 + kt] + biasL[r * 64 + 8 + kh] + biasL[r * 64 + 36 + kw];
                }
            }
            sv[i] = s;
            mx = fmaxf(mx, s);
        }
        #pragma unroll
        for (int off = 8; off >= 1; off >>= 1)
            mx = fmaxf(mx, __shfl_xor(mx, off));
        float mnew  = fmaxf(mrun, mx);
        float alpha = __expf(mrun - mnew);
        mrun = mnew;
        if (c0 == 0) alphL[r] = alpha;
        float psum = 0.f;
        #pragma unroll
        for (int i = 0; i < 4; ++i) {
            float p = __expf(sv[i] - mnew);
            psum += p;
            pls[r * 72 + c0 + i * 16] = f2b(p);
        }
        #pragma unroll
        for (int off = 8; off >= 1; off >>= 1)
            psum += __shfl_xor(psum, off);
        lrun = alpha * lrun + psum;
        __syncthreads();
        // ---- PV: rescale accumulators, then accumulate this tile ----
        {
            float a0 = alphL[quad * 4 + 0], a1 = alphL[quad * 4 + 1],
                  a2 = alphL[quad * 4 + 2], a3 = alphL[quad * 4 + 3];
            acc0[0] *= a0; acc0[1] *= a1; acc0[2] *= a2; acc0[3] *= a3;
            if (has2) { acc1[0] *= a0; acc1[1] *= a1; acc1[2] *= a2; acc1[3] *= a3; }
            #pragma unroll
            for (int kc = 0; kc < 2; ++kc) {
                bf16x8 ap  = *(const bf16x8*)(pls + l16 * 72 + kc * 32 + quad * 8);
                bf16x8 bv0 = *(const bf16x8*)(vls + (nt0 * 16 + l16) * 72 + kc * 32 + quad * 8);
                acc0 = __builtin_amdgcn_mfma_f32_16x16x32_bf16(ap, bv0, acc0, 0, 0, 0);
                if (has2) {
                    bf16x8 bv1 = *(const bf16x8*)(vls + (nt1 * 16 + l16) * 72 + kc * 32 + quad * 8);
                    acc1 = __builtin_amdgcn_mfma_f32_16x16x32_bf16(ap, bv1, acc1, 0, 0, 0);
                }
            }
        }
        __syncthreads();
    }
    if (c0 == 0) lrunL[r] = lrun;
    __syncthreads();
    // ---- epilogue: normalize, residual, store ----
    #pragma unroll
    for (int rr = 0; rr < 4; ++rr) {
        int row = quad * 4 + rr;
        int tok = q0 + row;
        if (tok >= NTOKS) continue;
        float inv = 1.f / lrunL[row];
        {
            int col = nt0 * 16 + l16;
            float val = acc0[rr] * inv;
            if (tok >= 1) val += qp[((size_t)h * NTOKS + tok) * HD + col];
            pre[(size_t)tok * DIM + h * HD + col] = val;
        }
        if (has2) {
            int col = nt1 * 16 + l16;
            float val = acc1[rr] * inv;
            if (tok >= 1) val += qp[((size_t)h * NTOKS + tok) * HD + col];
            pre[(size_t)tok * DIM + h * HD + col] = val;
        }
    }
}

// ---------------- Kernel 5: out = pre @ proj_w^T + proj_b ----------------
__global__ __launch_bounds__(192) void proj_gemm(
    const float* __restrict__ pre, const float* __restrict__ w,
    const float* __restrict__ b, float* __restrict__ out)
{
    __shared__ float xs[8][DIM];
    int row0 = blockIdx.x * 8;
    int t = threadIdx.x;
    for (int i = t; i < 8 * DIM; i += 192) {
        int r = i / DIM, c = i % DIM;
        xs[r][c] = (row0 + r < NTOKS) ? pre[(size_t)(row0 + r) * DIM + c] : 0.f;
    }
    __syncthreads();
    int j = t;  // 0..191
    const float4* wr = (const float4*)(w + (size_t)j * DIM);
    float acc[8];
    #pragma unroll
    for (int r = 0; r < 8; ++r) acc[r] = 0.f;
    for (int k4 = 0; k4 < DIM / 4; ++k4) {
        float4 wv = wr[k4];
        #pragma unroll
        for (int r = 0; r < 8; ++r) {
            acc[r] += xs[r][k4*4+0]*wv.x + xs[r][k4*4+1]*wv.y
                    + xs[r][k4*4+2]*wv.z + xs[r][k4*4+3]*wv.w;
        }
    }
    float bj = b[j];
    #pragma unroll
    for (int r = 0; r < 8; ++r) {
        int row = row0 + r;
        if (row < NTOKS) out[(size_t)row * DIM + j] = acc[r] + bj;
    }
}

extern "C" void kernel_launch(void* const* d_in, const int* in_sizes, int n_in,
                              void* d_out, int out_size, void* d_ws, size_t ws_size,
                              hipStream_t stream) {
    (void)in_sizes; (void)n_in; (void)out_size; (void)ws_size;
    const float* x      = (const float*)d_in[0];
    const float* qkv_w  = (const float*)d_in[1];
    const float* qkv_b  = (const float*)d_in[2];
    const float* proj_w = (const float*)d_in[3];
    const float* proj_b = (const float*)d_in[4];
    const float* pool_q = (const float*)d_in[5];
    const float* pool_k = (const float*)d_in[6];
    const float* pool_v = (const float*)d_in[7];
    const float* gq     = (const float*)d_in[8];
    const float* bq     = (const float*)d_in[9];
    const float* gk     = (const float*)d_in[10];
    const float* bk     = (const float*)d_in[11];
    const float* gv     = (const float*)d_in[12];
    const float* bv     = (const float*)d_in[13];
    const float* rel_h  = (const float*)d_in[14];
    const float* rel_w  = (const float*)d_in[15];
    const float* rel_t  = (const float*)d_in[16];

    char* p = (char*)d_ws;
    auto alloc = [&](size_t bytes) -> void* {
        void* r = (void*)p; p += (bytes + 255) & ~(size_t)255; return r;
    };
    float* qkv = (float*)alloc((size_t)NTOKS * 576 * 4);
    float* qp  = (float*)alloc((size_t)HEADS * NTOKS * HD * 4);
    u16*   qbb = (u16*)  alloc((size_t)HEADS * NTOKS * HD * 2);
    u16*   kbb = (u16*)  alloc((size_t)HEADS * NTOKS * HD * 2);
    u16*   vbb = (u16*)  alloc((size_t)HEADS * NTOKS * HD * 2);
    u16*   vbT = (u16*)  alloc((size_t)HEADS * HD * VT_LD * 2);
    float* bt  = (float*)alloc((size_t)HEADS * NSP * 8 * 4);
    float* bh  = (float*)alloc((size_t)HEADS * NSP * 28 * 4);
    float* bw  = (float*)alloc((size_t)HEADS * NSP * 28 * 4);
    float* pre = (float*)alloc((size_t)NTOKS * DIM * 4);

    qkv_gemm<<<(NTOKS + 7) / 8, 256, 0, stream>>>(x, qkv_w, qkv_b, qkv);
    pool_ln<<<dim3(HEADS * NTOKS, 3), 128, 0, stream>>>(
        qkv, pool_q, pool_k, pool_v, gq, bq, gk, bk, gv, bv, qp, qbb, kbb, vbb);
    vtrans<<<dim3((NTOKS + 127) / 128, HEADS), 256, 0, stream>>>(vbb, vbT);
    relbias<<<HEADS * NSP, 64, 0, stream>>>(qp, rel_h, rel_w, rel_t, bt, bh, bw);
    attn_mfma<<<HEADS * QB2, 256, 0, stream>>>(qbb, kbb, vbT, qp, bt, bh, bw, pre);
    proj_gemm<<<(NTOKS + 7) / 8, 192, 0, stream>>>(pre, proj_w, proj_b, (float*)d_out);
}